// Round 8
// baseline (265.737 us; speedup 1.0000x reference)
//
#include <hip/hip_runtime.h>
#include <math.h>

#define N_NODES 50000
#define N_FEAT  128
#define N_EDGES 600000
#define N_POWERS 3

#define PAIRS 5
#define EDGES_PER_BLK (64 * PAIRS)   // 320

#define NB64 64                      // j-buckets: bucket = j / NJB
#define NJB 782                      // j-values per bucket (63*782=49266; bucket 63 has 734)
#define CAP64 10240                  // per-bucket capacity (mean 9384, sigma 96 -> +9 sigma)
#define CHUNK 2048
#define NCHUNK 293                   // ceil(600000 / 2048)

typedef _Float16 half2v __attribute__((ext_vector_type(2)));
typedef unsigned u32x4  __attribute__((ext_vector_type(4)));
union HU { unsigned u; half2v h; };

// ---- conversion: x fp32 -> packed f16 rows; block 0 packs Wa; block 1 zeroes cur ----
__global__ __launch_bounds__(256) void conv_x_plain(const float* __restrict__ x,
                                                    unsigned* __restrict__ xh,
                                                    const float* __restrict__ Wa,
                                                    unsigned* __restrict__ wah,
                                                    int* __restrict__ cur) {
    const int t = blockIdx.x * 256 + threadIdx.x;   // 800000 threads exactly
    const float4* x4 = (const float4*)x;
    float4 a = x4[(size_t)t * 2];
    float4 b = x4[(size_t)t * 2 + 1];
    HU p0, p1, p2, p3;
    p0.h = half2v{(_Float16)a.x, (_Float16)a.y};
    p1.h = half2v{(_Float16)a.z, (_Float16)a.w};
    p2.h = half2v{(_Float16)b.x, (_Float16)b.y};
    p3.h = half2v{(_Float16)b.z, (_Float16)b.w};
    ((uint4*)xh)[t] = uint4{p0.u, p1.u, p2.u, p3.u};
    if (blockIdx.x == 0 && threadIdx.x < 192) {
        const int tt = threadIdx.x;
        #pragma unroll
        for (int q = 0; q < 3; ++q) {
            int idx = tt + q * 192;            // 576 entries: (p,k,c)
            int c  = idx % 3;
            int pk = idx / 3;
            int k  = pk % 64;
            int p  = pk / 64;
            float w0 = Wa[p * 384 + (2 * k) * 3 + c];
            float w1 = Wa[p * 384 + (2 * k + 1) * 3 + c];
            HU u; u.h = half2v{(_Float16)w0, (_Float16)w1};
            wah[idx] = u.u;
        }
    }
    if (cur != nullptr && blockIdx.x == 1 && threadIdx.x < N_POWERS * NB64)
        cur[threadIdx.x] = 0;
}

// ---- level-1: 64-bucket binning by j/782 (LDS-staged: all global writes coalesced) ----
__global__ __launch_bounds__(256) void scatter_onepass(const int* __restrict__ edge_index,
                                                       unsigned* __restrict__ su,
                                                       int* __restrict__ inv,
                                                       int* __restrict__ cur) {
    __shared__ int tot[4][NB64];
    __shared__ int sh_w[4][NB64];
    __shared__ int sh_lbase[NB64];
    __shared__ int sh_delta[NB64];
    __shared__ int sh_vt;
    __shared__ unsigned pay[CHUNK];
    __shared__ int dlt[CHUNK];

    const int p = blockIdx.y, chunk = blockIdx.x;
    const int tid  = threadIdx.x;
    const int lane = tid & 63;
    const int wave = tid >> 6;
    const int* ej = edge_index + (size_t)p * 2 * N_EDGES;
    const int* ei = ej + N_EDGES;
    const int base = chunk * CHUNK;

    int jj[8], ii[8], sbk[8], off[8];
    int run = 0;                       // lane L tracks running count of bucket L
    #pragma unroll
    for (int k = 0; k < 8; ++k) {
        const int e = base + k * 256 + tid;
        const bool valid = e < N_EDGES;
        jj[k] = __builtin_nontemporal_load(ej + (valid ? e : 0));
        ii[k] = __builtin_nontemporal_load(ei + (valid ? e : 0));
        const int b = jj[k] / NJB;
        sbk[k] = b;
        const unsigned long long m0 = __ballot(b & 1);
        const unsigned long long m1 = __ballot(b & 2);
        const unsigned long long m2 = __ballot(b & 4);
        const unsigned long long m3 = __ballot(b & 8);
        const unsigned long long m4 = __ballot(b & 16);
        const unsigned long long m5 = __ballot(b & 32);
        const unsigned long long vm = __ballot(valid);
        unsigned long long m = ((b & 1) ? m0 : ~m0);
        m &= ((b & 2)  ? m1 : ~m1);
        m &= ((b & 4)  ? m2 : ~m2);
        m &= ((b & 8)  ? m3 : ~m3);
        m &= ((b & 16) ? m4 : ~m4);
        m &= ((b & 32) ? m5 : ~m5);
        m &= vm;
        const int rank = (int)__popcll(m & ((1ull << lane) - 1ull));
        unsigned long long mm = ((lane & 1) ? m0 : ~m0);
        mm &= ((lane & 2)  ? m1 : ~m1);
        mm &= ((lane & 4)  ? m2 : ~m2);
        mm &= ((lane & 8)  ? m3 : ~m3);
        mm &= ((lane & 16) ? m4 : ~m4);
        mm &= ((lane & 32) ? m5 : ~m5);
        mm &= vm;
        const int cnt = (int)__popcll(mm);      // count for bucket == lane
        const int pre = __shfl(run, b, 64);     // my bucket's running count (iters < k)
        off[k] = pre + rank;
        run += cnt;
    }
    tot[wave][lane] = run;
    __syncthreads();

    if (tid < NB64) {                           // wave 0: per-bucket cross-wave scan
        const int t0 = tot[0][tid], t1 = tot[1][tid], t2 = tot[2][tid], t3 = tot[3][tid];
        const int bt = t0 + t1 + t2 + t3;
        int s = bt;                             // inclusive scan over 64 buckets
        #pragma unroll
        for (int d = 1; d < 64; d <<= 1) {
            int u = __shfl_up(s, d, 64);
            if (tid >= d) s += u;
        }
        const int lb = s - bt;                  // LDS packing base for this bucket
        const int g  = atomicAdd(&cur[p * NB64 + tid], bt);
        sh_lbase[tid] = lb;
        sh_delta[tid] = (p * NB64 + tid) * CAP64 + g - lb;   // global slot = delta + pos
        sh_w[0][tid] = 0;
        sh_w[1][tid] = t0;
        sh_w[2][tid] = t0 + t1;
        sh_w[3][tid] = t0 + t1 + t2;
        if (tid == 63) sh_vt = lb + bt;
    }
    __syncthreads();

    #pragma unroll
    for (int k = 0; k < 8; ++k) {               // pack bucket-contiguous into LDS
        const int e = base + k * 256 + tid;
        if (e < N_EDGES) {
            const int b = sbk[k];
            const int pos = sh_lbase[b] + sh_w[wave][b] + off[k];
            pay[pos] = (unsigned)(jj[k] | (ii[k] << 16));
            dlt[pos] = sh_delta[b];
            inv[(size_t)p * N_EDGES + e] = sh_delta[b] + pos;   // coalesced (e-order)
        }
    }
    __syncthreads();

    const int vt = sh_vt;                       // coalesced flush (runs of ~32 slots)
    #pragma unroll
    for (int k = 0; k < 8; ++k) {
        const int pos = k * 256 + tid;
        if (pos < vt)
            su[(size_t)(dlt[pos] + pos)] = pay[pos];
    }
}

// ---- level-2: full j-sort within each bucket (counting sort, all-coalesced I/O) ----
// perm (scratch = d_out, compact layout): perm[p*N_EDGES + csum(b) + oldpos] = newpos.
__global__ __launch_bounds__(256) void sortj_kernel(unsigned* __restrict__ su,
                                                    int* __restrict__ perm,
                                                    const int* __restrict__ cur) {
    __shared__ int hist[NJB];
    __shared__ unsigned spay[CAP64];            // 40 KB
    __shared__ int wsum[4];
    __shared__ int csum;
    const int p = blockIdx.y, b = blockIdx.x;
    const int tid = threadIdx.x;
    const int count = cur[p * NB64 + b];
    const size_t gbase = (size_t)(p * NB64 + b) * CAP64;

    if (tid == 0) {
        int s = 0;
        for (int t = 0; t < b; ++t) s += cur[p * NB64 + t];
        csum = s;
    }
    for (int t = tid; t < NJB; t += 256) hist[t] = 0;
    __syncthreads();

    const int j0 = b * NJB;
    for (int s = tid; s < count; s += 256) {
        const unsigned v = su[gbase + s];
        atomicAdd(&hist[(int)(v & 0xFFFFu) - j0], 1);
    }
    __syncthreads();

    // exclusive scan of hist[0..NJB): thread t owns [4t, 4t+4)
    int loc[4]; int ts = 0;
    #pragma unroll
    for (int q = 0; q < 4; ++q) {
        const int idx = tid * 4 + q;
        loc[q] = (idx < NJB) ? hist[idx] : 0;
        ts += loc[q];
    }
    const int lane = tid & 63, wv = tid >> 6;
    int ps = ts;
    #pragma unroll
    for (int d = 1; d < 64; d <<= 1) { int u = __shfl_up(ps, d, 64); if (lane >= d) ps += u; }
    if (lane == 63) wsum[wv] = ps;
    __syncthreads();
    int wbase = 0;
    #pragma unroll
    for (int wq = 0; wq < 4; ++wq) wbase += (wq < wv) ? wsum[wq] : 0;
    int run = wbase + (ps - ts);
    __syncthreads();                            // all loc reads done before overwrite
    #pragma unroll
    for (int q = 0; q < 4; ++q) {
        const int idx = tid * 4 + q;
        if (idx < NJB) hist[idx] = run;
        run += loc[q];
    }
    __syncthreads();

    const int cb = p * N_EDGES + csum;
    for (int s = tid; s < count; s += 256) {    // re-read (L2-hot), place, record perm
        const unsigned v = su[gbase + s];
        const int np = atomicAdd(&hist[(int)(v & 0xFFFFu) - j0], 1);
        spay[np] = v;
        perm[cb + s] = np;                      // coalesced in s
    }
    __syncthreads();
    for (int s = tid; s < count; s += 256)      // coalesced flush of sorted payload
        su[gbase + s] = spay[s];
}

// ---- compose: inv[e] <- sorted global slot (frees perm scratch before adj) ----
__global__ __launch_bounds__(256) void fixinv_kernel(int* __restrict__ inv,
                                                     const int* __restrict__ perm,
                                                     const int* __restrict__ cur) {
    __shared__ int cbase[N_POWERS * NB64];
    const int tid = threadIdx.x;
    if (tid < N_POWERS * NB64) {
        const int p = tid / NB64, b = tid % NB64;
        int s = 0;
        for (int t = 0; t < b; ++t) s += cur[p * NB64 + t];
        cbase[tid] = p * N_EDGES + s;
    }
    __syncthreads();
    const int p = blockIdx.y;
    const int e = blockIdx.x * 256 + tid;
    if (e >= N_EDGES) return;
    const int g = inv[(size_t)p * N_EDGES + e];
    const int pb = g / CAP64;
    const int pos = g - pb * CAP64;
    const int np = perm[cbase[pb] + pos];       // gather (L2/L3-warm)
    inv[(size_t)p * N_EDGES + e] = pb * CAP64 + np;
}

template<int PAT>
__device__ __forceinline__ float swz(float v) {
    return __int_as_float(__builtin_amdgcn_ds_swizzle(__float_as_int(v), PAT));
}

__device__ __forceinline__ void dot3_8(const u32x4& qa0, const u32x4& qa1,
                                       const u32x4& qb0, const u32x4& qb1,
                                       const HU wa[8][3],
                                       float& h0, float& h1, float& h2) {
    unsigned ua[8] = {qa0[0], qa0[1], qa0[2], qa0[3], qa1[0], qa1[1], qa1[2], qa1[3]};
    unsigned ub[8] = {qb0[0], qb0[1], qb0[2], qb0[3], qb1[0], qb1[1], qb1[2], qb1[3]};
    h0 = 0.f; h1 = 0.f; h2 = 0.f;
    #pragma unroll
    for (int k = 0; k < 8; ++k) {
        HU a, b, d;
        a.u = ua[k]; b.u = ub[k];
        d.h = a.h - b.h;
        d.u &= 0x7fff7fffu;               // packed abs
        h0 = __builtin_amdgcn_fdot2(d.h, wa[k][0].h, h0, false);
        h1 = __builtin_amdgcn_fdot2(d.h, wa[k][1].h, h1, false);
        h2 = __builtin_amdgcn_fdot2(d.h, wa[k][2].h, h2, false);
    }
}

// Main: su fully j-sorted within each 782-j bucket (runs ~12). A wave's 8-slot window
// hits 1-2 distinct j rows (coalescer dedups in-instruction); a block's 320 edges touch
// ~27 j rows (7 KB, L1-resident). i-rows nontemporal (single-use, keep L1 for j).
// bid = k*64 + sb -> XCD = sb&7 pins each bucket's 32 blocks to one XCD (j-slice in L2).
// r5's MLP-8 pipelined body (q-hoist + next-iter row prefetch, VGPR~48): r7 proved the
// low-VGPR variant serializes gathers (28 VGPR -> 94 us); MLP > occupancy here.
__global__ __launch_bounds__(256, 4) void adj_kernel_sorted(
    const unsigned* __restrict__ xh,
    unsigned* su,                       // in: j|i<<16 per slot (sorted); out: w bits
    const int* __restrict__ cur,
    const unsigned* __restrict__ wah,
    const float* __restrict__ ba,
    const float* __restrict__ Wb,
    const float* __restrict__ bb)
{
    const int p    = blockIdx.y;
    const int sb   = blockIdx.x & 63;
    const int k    = blockIdx.x >> 6;
    const int tid  = threadIdx.x;
    const int lane = tid & 63;
    const int wave = tid >> 6;
    const int sub  = lane & 7;
    const int grp  = lane >> 3;

    const int count = cur[p * NB64 + sb];
    const int base  = k * EDGES_PER_BLK;
    if (base >= count) return;

    HU wa[8][3];
    {
        const unsigned* wp = wah + ((size_t)p * 64 + sub * 8) * 3;
        #pragma unroll
        for (int kk = 0; kk < 8; ++kk) {
            wa[kk][0].u = wp[kk * 3 + 0];
            wa[kk][1].u = wp[kk * 3 + 1];
            wa[kk][2].u = wp[kk * 3 + 2];
        }
        #pragma unroll
        for (int kk = 0; kk < 8; ++kk) {
            asm volatile("" : "+v"(wa[kk][0].u), "+v"(wa[kk][1].u), "+v"(wa[kk][2].u));
        }
    }

    const float ba0 = ba[p * 3 + 0], ba1 = ba[p * 3 + 1], ba2 = ba[p * 3 + 2];
    const float wb0 = Wb[p * 3 + 0], wb1 = Wb[p * 3 + 1], wb2 = Wb[p * 3 + 2];
    const float bbp = bb[p];

    unsigned* sup = su + (size_t)(p * NB64 + sb) * CAP64;

    const int eoff = wave * 8 + grp;
    const int roff = sub * 8;
    const int cm1  = count - 1;

    // prologue: all 10 su loads issue immediately (independent addresses)
    unsigned q[2 * PAIRS];
    #pragma unroll
    for (int it = 0; it < PAIRS; ++it) {
        const int r1 = base + it * 64 + eoff;
        q[2 * it]     = __builtin_nontemporal_load(sup + min(r1, cm1));
        q[2 * it + 1] = __builtin_nontemporal_load(sup + min(r1 + 32, cm1));
    }

    u32x4 A0, A1, B0, B1, C0, C1, D0, D1;
    {
        const int j1 = (int)(q[0] & 0xFFFFu), i1 = (int)(q[0] >> 16);
        const int j2 = (int)(q[1] & 0xFFFFu), i2 = (int)(q[1] >> 16);
        const u32x4* rj1 = (const u32x4*)(xh + ((size_t)j1 << 6) + roff);
        const u32x4* ri1 = (const u32x4*)(xh + ((size_t)i1 << 6) + roff);
        const u32x4* rj2 = (const u32x4*)(xh + ((size_t)j2 << 6) + roff);
        const u32x4* ri2 = (const u32x4*)(xh + ((size_t)i2 << 6) + roff);
        A0 = rj1[0]; A1 = rj1[1];
        B0 = __builtin_nontemporal_load(ri1); B1 = __builtin_nontemporal_load(ri1 + 1);
        C0 = rj2[0]; C1 = rj2[1];
        D0 = __builtin_nontemporal_load(ri2); D1 = __builtin_nontemporal_load(ri2 + 1);
    }

    #pragma unroll
    for (int it = 0; it < PAIRS; ++it) {
        u32x4 nA0, nA1, nB0, nB1, nC0, nC1, nD0, nD1;
        if (it + 1 < PAIRS) {
            const int j1 = (int)(q[2 * it + 2] & 0xFFFFu), i1 = (int)(q[2 * it + 2] >> 16);
            const int j2 = (int)(q[2 * it + 3] & 0xFFFFu), i2 = (int)(q[2 * it + 3] >> 16);
            const u32x4* rj1 = (const u32x4*)(xh + ((size_t)j1 << 6) + roff);
            const u32x4* ri1 = (const u32x4*)(xh + ((size_t)i1 << 6) + roff);
            const u32x4* rj2 = (const u32x4*)(xh + ((size_t)j2 << 6) + roff);
            const u32x4* ri2 = (const u32x4*)(xh + ((size_t)i2 << 6) + roff);
            nA0 = rj1[0]; nA1 = rj1[1];
            nB0 = __builtin_nontemporal_load(ri1); nB1 = __builtin_nontemporal_load(ri1 + 1);
            nC0 = rj2[0]; nC1 = rj2[1];
            nD0 = __builtin_nontemporal_load(ri2); nD1 = __builtin_nontemporal_load(ri2 + 1);
        }

        float h0a, h1a, h2a, h0b, h1b, h2b;
        dot3_8(A0, A1, B0, B1, wa, h0a, h1a, h2a);
        dot3_8(C0, C1, D0, D1, wa, h0b, h1b, h2b);

        h0a += swz<0x041F>(h0a); h1a += swz<0x041F>(h1a); h2a += swz<0x041F>(h2a);
        h0b += swz<0x041F>(h0b); h1b += swz<0x041F>(h1b); h2b += swz<0x041F>(h2b);
        h0a += swz<0x081F>(h0a); h1a += swz<0x081F>(h1a); h2a += swz<0x081F>(h2a);
        h0b += swz<0x081F>(h0b); h1b += swz<0x081F>(h1b); h2b += swz<0x081F>(h2b);
        h0a += swz<0x101F>(h0a); h1a += swz<0x101F>(h1a); h2a += swz<0x101F>(h2a);
        h0b += swz<0x101F>(h0b); h1b += swz<0x101F>(h1b); h2b += swz<0x101F>(h2b);

        if (sub == 0) {
            const int r1 = base + it * 64 + eoff;
            const int r2 = r1 + 32;
            if (r1 < count) {
                float r0  = fmaxf(h0a + ba0, 0.f);
                float r1f = fmaxf(h1a + ba1, 0.f);
                float r2f = fmaxf(h2a + ba2, 0.f);
                float s   = fmaf(r0, wb0, fmaf(r1f, wb1, fmaf(r2f, wb2, bbp)));
                ((float*)sup)[r1] = 1.f / (1.f + __expf(-s));
            }
            if (r2 < count) {
                float r0  = fmaxf(h0b + ba0, 0.f);
                float r1f = fmaxf(h1b + ba1, 0.f);
                float r2f = fmaxf(h2b + ba2, 0.f);
                float s   = fmaf(r0, wb0, fmaf(r1f, wb1, fmaf(r2f, wb2, bbp)));
                ((float*)sup)[r2] = 1.f / (1.f + __expf(-s));
            }
        }

        if (it + 1 < PAIRS) {
            A0 = nA0; A1 = nA1; B0 = nB0; B1 = nB1;
            C0 = nC0; C1 = nC1; D0 = nD0; D1 = nD1;
        }
    }
}

// ---- final: out[e] = w[inv[e]] ; coalesced inv read + out write, warm gather ----
__global__ __launch_bounds__(256) void unscatter_kernel(const unsigned* __restrict__ su,
                                                        const int* __restrict__ inv,
                                                        float* __restrict__ out) {
    const int p  = blockIdx.y;
    const int t4 = (blockIdx.x * 256 + threadIdx.x) * 4;
    if (t4 >= N_EDGES) return;
    const int4 iv = *(const int4*)(inv + (size_t)p * N_EDGES + t4);
    const float* w = (const float*)su;          // inv holds sorted GLOBAL slot indices
    float4 o;
    o.x = w[iv.x]; o.y = w[iv.y]; o.z = w[iv.z]; o.w = w[iv.w];
    __builtin_nontemporal_store(o.x, out + (size_t)p * N_EDGES + t4 + 0);
    __builtin_nontemporal_store(o.y, out + (size_t)p * N_EDGES + t4 + 1);
    __builtin_nontemporal_store(o.z, out + (size_t)p * N_EDGES + t4 + 2);
    __builtin_nontemporal_store(o.w, out + (size_t)p * N_EDGES + t4 + 3);
}

// ---- round-4 path (no sorting) for mid-size ws ----
__global__ __launch_bounds__(256) void adj_kernel_f16(
    const unsigned* __restrict__ xh,
    const unsigned* __restrict__ wah,
    const int*   __restrict__ edge_index,
    const float* __restrict__ ba,
    const float* __restrict__ Wb,
    const float* __restrict__ bb,
    float* __restrict__ out)
{
    const int p    = blockIdx.y;
    const int tid  = threadIdx.x;
    const int lane = tid & 63;
    const int wave = tid >> 6;
    const int sub  = lane & 7;
    const int grp  = lane >> 3;

    HU wa[8][3];
    {
        const unsigned* wp = wah + ((size_t)p * 64 + sub * 8) * 3;
        #pragma unroll
        for (int k = 0; k < 8; ++k) {
            wa[k][0].u = wp[k * 3 + 0];
            wa[k][1].u = wp[k * 3 + 1];
            wa[k][2].u = wp[k * 3 + 2];
        }
        #pragma unroll
        for (int k = 0; k < 8; ++k) {
            asm volatile("" : "+v"(wa[k][0].u), "+v"(wa[k][1].u), "+v"(wa[k][2].u));
        }
    }

    const float ba0 = ba[p * 3 + 0], ba1 = ba[p * 3 + 1], ba2 = ba[p * 3 + 2];
    const float wb0 = Wb[p * 3 + 0], wb1 = Wb[p * 3 + 1], wb2 = Wb[p * 3 + 2];
    const float bbp = bb[p];

    const int* ej = edge_index + (size_t)p * 2 * N_EDGES;
    const int* ei = ej + N_EDGES;
    float* outp = out + (size_t)p * N_EDGES;

    const int e_blk = blockIdx.x * EDGES_PER_BLK;
    const int eoff  = wave * 8 + grp;
    const int roff  = sub * 8;

    #pragma unroll
    for (int it = 0; it < PAIRS; ++it) {
        const int e1 = e_blk + it * 64 + eoff;
        const int e2 = e1 + 32;
        const int j1 = __builtin_nontemporal_load(ej + e1);
        const int i1 = __builtin_nontemporal_load(ei + e1);
        const int j2 = __builtin_nontemporal_load(ej + e2);
        const int i2 = __builtin_nontemporal_load(ei + e2);

        const u32x4* rj1 = (const u32x4*)(xh + ((size_t)j1 << 6) + roff);
        const u32x4* ri1 = (const u32x4*)(xh + ((size_t)i1 << 6) + roff);
        const u32x4* rj2 = (const u32x4*)(xh + ((size_t)j2 << 6) + roff);
        const u32x4* ri2 = (const u32x4*)(xh + ((size_t)i2 << 6) + roff);
        u32x4 a0 = rj1[0], a1 = rj1[1];
        u32x4 b0 = ri1[0], b1 = ri1[1];
        u32x4 c0 = rj2[0], c1 = rj2[1];
        u32x4 d0 = ri2[0], d1 = ri2[1];

        float h0a, h1a, h2a, h0b, h1b, h2b;
        dot3_8(a0, a1, b0, b1, wa, h0a, h1a, h2a);
        dot3_8(c0, c1, d0, d1, wa, h0b, h1b, h2b);

        h0a += swz<0x041F>(h0a); h1a += swz<0x041F>(h1a); h2a += swz<0x041F>(h2a);
        h0b += swz<0x041F>(h0b); h1b += swz<0x041F>(h1b); h2b += swz<0x041F>(h2b);
        h0a += swz<0x081F>(h0a); h1a += swz<0x081F>(h1a); h2a += swz<0x081F>(h2a);
        h0b += swz<0x081F>(h0b); h1b += swz<0x081F>(h1b); h2b += swz<0x081F>(h2b);
        h0a += swz<0x101F>(h0a); h1a += swz<0x101F>(h1a); h2a += swz<0x101F>(h2a);
        h0b += swz<0x101F>(h0b); h1b += swz<0x101F>(h1b); h2b += swz<0x101F>(h2b);

        if (sub == 0) {
            float r0 = fmaxf(h0a + ba0, 0.f);
            float r1 = fmaxf(h1a + ba1, 0.f);
            float r2 = fmaxf(h2a + ba2, 0.f);
            float s  = fmaf(r0, wb0, fmaf(r1, wb1, fmaf(r2, wb2, bbp)));
            __builtin_nontemporal_store(1.f / (1.f + __expf(-s)), outp + e1);
            r0 = fmaxf(h0b + ba0, 0.f);
            r1 = fmaxf(h1b + ba1, 0.f);
            r2 = fmaxf(h2b + ba2, 0.f);
            s  = fmaf(r0, wb0, fmaf(r1, wb1, fmaf(r2, wb2, bbp)));
            __builtin_nontemporal_store(1.f / (1.f + __expf(-s)), outp + e2);
        }
    }
}

// ---- fp32 fallback (no workspace) ----
__global__ __launch_bounds__(256) void adj_kernel_f32(
    const float* __restrict__ x,
    const int*   __restrict__ edge_index,
    const float* __restrict__ Wa,
    const float* __restrict__ ba,
    const float* __restrict__ Wb,
    const float* __restrict__ bb,
    float* __restrict__ out)
{
    const int p    = blockIdx.y;
    const int tid  = threadIdx.x;
    const int lane = tid & 63;
    const int wave = tid >> 6;
    const int sub  = lane & 15;
    const int grp  = lane >> 4;
    const int f0 = sub * 8;

    const float* Wap = Wa + (size_t)p * N_FEAT * 3;
    float wa0[8], wa1[8], wa2[8];
    #pragma unroll
    for (int k = 0; k < 8; ++k) {
        wa0[k] = Wap[(f0 + k) * 3 + 0];
        wa1[k] = Wap[(f0 + k) * 3 + 1];
        wa2[k] = Wap[(f0 + k) * 3 + 2];
    }
    const float ba0 = ba[p * 3 + 0], ba1 = ba[p * 3 + 1], ba2 = ba[p * 3 + 2];
    const float wb0 = Wb[p * 3 + 0], wb1 = Wb[p * 3 + 1], wb2 = Wb[p * 3 + 2];
    const float bbp = bb[p];

    const int e = blockIdx.x * 16 + wave * 4 + grp;
    const int* ej = edge_index + (size_t)p * 2 * N_EDGES;
    const int* ei = ej + N_EDGES;
    const int j = ej[e];
    const int i = ei[e];

    const float4* xj = (const float4*)(x + (size_t)j * N_FEAT + f0);
    const float4* xi = (const float4*)(x + (size_t)i * N_FEAT + f0);
    float4 a0 = xj[0], a1 = xj[1];
    float4 b0 = xi[0], b1 = xi[1];

    float d[8];
    d[0] = fabsf(a0.x - b0.x); d[1] = fabsf(a0.y - b0.y);
    d[2] = fabsf(a0.z - b0.z); d[3] = fabsf(a0.w - b0.w);
    d[4] = fabsf(a1.x - b1.x); d[5] = fabsf(a1.y - b1.y);
    d[6] = fabsf(a1.z - b1.z); d[7] = fabsf(a1.w - b1.w);

    float h0 = 0.f, h1 = 0.f, h2 = 0.f;
    #pragma unroll
    for (int k = 0; k < 8; ++k) {
        h0 = fmaf(d[k], wa0[k], h0);
        h1 = fmaf(d[k], wa1[k], h1);
        h2 = fmaf(d[k], wa2[k], h2);
    }
    #pragma unroll
    for (int m = 1; m < 16; m <<= 1) {
        h0 += __shfl_xor(h0, m, 64);
        h1 += __shfl_xor(h1, m, 64);
        h2 += __shfl_xor(h2, m, 64);
    }
    if (sub == 0) {
        float r0 = fmaxf(h0 + ba0, 0.f);
        float r1 = fmaxf(h1 + ba1, 0.f);
        float r2 = fmaxf(h2 + ba2, 0.f);
        float s  = fmaf(r0, wb0, fmaf(r1, wb1, fmaf(r2, wb2, bbp)));
        float w  = 1.f / (1.f + expf(-s));
        out[(size_t)p * N_EDGES + e] = w;
    }
}

extern "C" void kernel_launch(void* const* d_in, const int* in_sizes, int n_in,
                              void* d_out, int out_size, void* d_ws, size_t ws_size,
                              hipStream_t stream) {
    const float* x          = (const float*)d_in[0];
    const int*   edge_index = (const int*)d_in[1];
    const float* Wa         = (const float*)d_in[2];
    const float* ba         = (const float*)d_in[3];
    const float* Wb         = (const float*)d_in[4];
    const float* bb         = (const float*)d_in[5];
    float* out = (float*)d_out;

    const size_t x_bytes   = (size_t)N_NODES * N_FEAT * 2;          // 12,800,000
    const size_t su_bytes  = (size_t)N_POWERS * NB64 * CAP64 * 4;   //  7,864,320
    const size_t inv_bytes = (size_t)N_POWERS * N_EDGES * 4;        //  7,200,000
    const size_t wa_bytes  = 2304;
    const size_t cur_bytes = N_POWERS * NB64 * 4;                   //        768
    const size_t need_full = x_bytes + su_bytes + inv_bytes + wa_bytes + cur_bytes; // 27,867,392

    if (ws_size >= need_full) {
        char* w = (char*)d_ws;
        unsigned* xh  = (unsigned*)w;
        unsigned* su  = (unsigned*)(w + x_bytes);
        int*      inv = (int*)(w + x_bytes + su_bytes);
        unsigned* wah = (unsigned*)(w + x_bytes + su_bytes + inv_bytes);
        int*      cur = (int*)(w + x_bytes + su_bytes + inv_bytes + wa_bytes);
        int*      perm = (int*)out;   // d_out as scratch; consumed by fixinv before adj,
                                      // fully overwritten by unscatter at the end.

        conv_x_plain<<<N_NODES * N_FEAT / 2048, 256, 0, stream>>>(x, xh, Wa, wah, cur);
        scatter_onepass<<<dim3(NCHUNK, N_POWERS), 256, 0, stream>>>(edge_index, su, inv, cur);
        sortj_kernel<<<dim3(NB64, N_POWERS), 256, 0, stream>>>(su, perm, cur);
        fixinv_kernel<<<dim3((N_EDGES + 255) / 256, N_POWERS), 256, 0, stream>>>(inv, perm, cur);
        dim3 grid(NB64 * (CAP64 / EDGES_PER_BLK), N_POWERS);   // (2048, 3)
        adj_kernel_sorted<<<grid, 256, 0, stream>>>(xh, su, cur, wah, ba, Wb, bb);
        unscatter_kernel<<<dim3((N_EDGES / 4 + 255) / 256, N_POWERS), 256, 0, stream>>>(
            su, inv, out);
    } else if (ws_size >= x_bytes + wa_bytes) {
        unsigned* xh  = (unsigned*)d_ws;
        unsigned* wah = (unsigned*)((char*)d_ws + x_bytes);
        conv_x_plain<<<N_NODES * N_FEAT / 2048, 256, 0, stream>>>(x, xh, Wa, wah, nullptr);
        dim3 grid(N_EDGES / EDGES_PER_BLK, N_POWERS);
        adj_kernel_f16<<<grid, 256, 0, stream>>>(xh, wah, edge_index, ba, Wb, bb, out);
    } else {
        dim3 grid((N_EDGES + 15) / 16, N_POWERS);
        adj_kernel_f32<<<grid, 256, 0, stream>>>(x, edge_index, Wa, ba, Wb, bb, out);
    }
}

// Round 9
// 174.670 us; speedup vs baseline: 1.5214x; 1.5214x over previous
//
#include <hip/hip_runtime.h>
#include <math.h>

#define N_NODES 50000
#define N_FEAT  128
#define N_EDGES 600000
#define N_POWERS 3

#define PAIRS 5
#define EDGES_PER_BLK (64 * PAIRS)   // 320

#define NB 128                       // (j,i) pair buckets: (j/6250)*16 + i/3125
#define CAPB 5120                    // per-bucket capacity (mean 4688, +6.3 sigma)
#define CHUNK 2048
#define NCHUNK 293                   // ceil(600000 / 2048)

typedef _Float16 half2v __attribute__((ext_vector_type(2)));
typedef unsigned u32x4  __attribute__((ext_vector_type(4)));
union HU { unsigned u; half2v h; };

// ---- conversion: x fp32 -> packed f16 rows; block 0 packs Wa; block 1 zeroes cur ----
__global__ __launch_bounds__(256) void conv_x_plain(const float* __restrict__ x,
                                                    unsigned* __restrict__ xh,
                                                    const float* __restrict__ Wa,
                                                    unsigned* __restrict__ wah,
                                                    int* __restrict__ cur) {
    const int t = blockIdx.x * 256 + threadIdx.x;   // 800000 threads exactly
    const float4* x4 = (const float4*)x;
    float4 a = x4[(size_t)t * 2];
    float4 b = x4[(size_t)t * 2 + 1];
    HU p0, p1, p2, p3;
    p0.h = half2v{(_Float16)a.x, (_Float16)a.y};
    p1.h = half2v{(_Float16)a.z, (_Float16)a.w};
    p2.h = half2v{(_Float16)b.x, (_Float16)b.y};
    p3.h = half2v{(_Float16)b.z, (_Float16)b.w};
    ((uint4*)xh)[t] = uint4{p0.u, p1.u, p2.u, p3.u};
    if (blockIdx.x == 0 && threadIdx.x < 192) {
        const int tt = threadIdx.x;
        #pragma unroll
        for (int q = 0; q < 3; ++q) {
            int idx = tt + q * 192;            // 576 entries: (p,k,c)
            int c  = idx % 3;
            int pk = idx / 3;
            int k  = pk % 64;
            int p  = pk / 64;
            float w0 = Wa[p * 384 + (2 * k) * 3 + c];
            float w1 = Wa[p * 384 + (2 * k + 1) * 3 + c];
            HU u; u.h = half2v{(_Float16)w0, (_Float16)w1};
            wah[idx] = u.u;
        }
    }
    if (cur != nullptr && blockIdx.x == 1)
        for (int tt = threadIdx.x; tt < N_POWERS * NB; tt += 256)
            cur[tt] = 0;
}

// ---- single-pass 128-bucket binning: 7-ballot ranking + block scan + 1 atomic/bucket ----
// LDS-staged so ALL su writes are coalesced (scattered partial-line writes cost ~8-16x:
// cross-XCD line bounce, r4 evidence). Emits inv[e]=global slot in e-order (coalesced).
__global__ __launch_bounds__(256) void scatter_onepass(const int* __restrict__ edge_index,
                                                       unsigned* __restrict__ su,
                                                       int* __restrict__ inv,
                                                       int* __restrict__ cur) {
    __shared__ int tot[4][NB];
    __shared__ int sh_w[4][NB];
    __shared__ int sh_lbase[NB];
    __shared__ int sh_delta[NB];
    __shared__ int sc[NB];
    __shared__ int sh_vt;
    __shared__ unsigned pay[CHUNK];
    __shared__ int dlt[CHUNK];

    const int p = blockIdx.y, chunk = blockIdx.x;
    const int tid  = threadIdx.x;
    const int lane = tid & 63;
    const int wave = tid >> 6;
    const int* ej = edge_index + (size_t)p * 2 * N_EDGES;
    const int* ei = ej + N_EDGES;
    const int base = chunk * CHUNK;

    int jj[8], ii[8], sbk[8], off[8];
    int runA = 0, runB = 0;            // lane L tracks buckets L and L+64
    #pragma unroll
    for (int k = 0; k < 8; ++k) {
        const int e = base + k * 256 + tid;
        const bool valid = e < N_EDGES;
        jj[k] = __builtin_nontemporal_load(ej + (valid ? e : 0));
        ii[k] = __builtin_nontemporal_load(ei + (valid ? e : 0));
        const int b = (jj[k] / 6250) * 16 + (ii[k] / 3125);
        sbk[k] = b;
        const unsigned long long m0 = __ballot(b & 1);
        const unsigned long long m1 = __ballot(b & 2);
        const unsigned long long m2 = __ballot(b & 4);
        const unsigned long long m3 = __ballot(b & 8);
        const unsigned long long m4 = __ballot(b & 16);
        const unsigned long long m5 = __ballot(b & 32);
        const unsigned long long m6 = __ballot(b & 64);
        const unsigned long long vm = __ballot(valid);
        unsigned long long m = ((b & 1) ? m0 : ~m0);
        m &= ((b & 2)  ? m1 : ~m1);
        m &= ((b & 4)  ? m2 : ~m2);
        m &= ((b & 8)  ? m3 : ~m3);
        m &= ((b & 16) ? m4 : ~m4);
        m &= ((b & 32) ? m5 : ~m5);
        m &= ((b & 64) ? m6 : ~m6);
        m &= vm;
        const int rank = (int)__popcll(m & ((1ull << lane) - 1ull));
        // masks for buckets (lane) and (lane+64): bits 0..5 match lane, bit 6 selects
        unsigned long long cm = ((lane & 1) ? m0 : ~m0);
        cm &= ((lane & 2)  ? m1 : ~m1);
        cm &= ((lane & 4)  ? m2 : ~m2);
        cm &= ((lane & 8)  ? m3 : ~m3);
        cm &= ((lane & 16) ? m4 : ~m4);
        cm &= ((lane & 32) ? m5 : ~m5);
        cm &= vm;
        const int cntA = (int)__popcll(cm & ~m6);
        const int cntB = (int)__popcll(cm & m6);
        const int preA = __shfl(runA, b & 63, 64);
        const int preB = __shfl(runB, b & 63, 64);
        off[k] = ((b & 64) ? preB : preA) + rank;
        runA += cntA; runB += cntB;
    }
    tot[wave][lane]      = runA;
    tot[wave][lane + 64] = runB;
    __syncthreads();

    int bt = 0;
    if (tid < NB) {
        const int t0 = tot[0][tid], t1 = tot[1][tid], t2 = tot[2][tid], t3 = tot[3][tid];
        bt = t0 + t1 + t2 + t3;
        sc[tid] = bt;
        sh_w[0][tid] = 0;
        sh_w[1][tid] = t0;
        sh_w[2][tid] = t0 + t1;
        sh_w[3][tid] = t0 + t1 + t2;
    }
    __syncthreads();
    #pragma unroll
    for (int d = 1; d < NB; d <<= 1) {          // Hillis-Steele inclusive scan, 128 wide
        int v = 0;
        if (tid < NB && tid >= d) v = sc[tid - d];
        __syncthreads();
        if (tid < NB) sc[tid] += v;
        __syncthreads();
    }
    if (tid < NB) {
        const int lb = sc[tid] - bt;            // LDS packing base for this bucket
        const int g  = atomicAdd(&cur[p * NB + tid], bt);
        sh_lbase[tid] = lb;
        sh_delta[tid] = (p * NB + tid) * CAPB + g - lb;   // global slot = delta + pos
        if (tid == NB - 1) sh_vt = lb + bt;
    }
    __syncthreads();

    #pragma unroll
    for (int k = 0; k < 8; ++k) {               // pack bucket-contiguous into LDS
        const int e = base + k * 256 + tid;
        if (e < N_EDGES) {
            const int b = sbk[k];
            const int pos = sh_lbase[b] + sh_w[wave][b] + off[k];
            pay[pos] = (unsigned)(jj[k] | (ii[k] << 16));
            dlt[pos] = sh_delta[b];
            inv[(size_t)p * N_EDGES + e] = sh_delta[b] + pos;   // coalesced (e-order)
        }
    }
    __syncthreads();

    const int vt = sh_vt;                       // coalesced flush (runs of ~16 slots)
    #pragma unroll
    for (int k = 0; k < 8; ++k) {
        const int pos = k * 256 + tid;
        if (pos < vt)
            su[(size_t)(dlt[pos] + pos)] = pay[pos];
    }
}

template<int PAT>
__device__ __forceinline__ float swz(float v) {
    return __int_as_float(__builtin_amdgcn_ds_swizzle(__float_as_int(v), PAT));
}

__device__ __forceinline__ void dot3_8(const u32x4& qa0, const u32x4& qa1,
                                       const u32x4& qb0, const u32x4& qb1,
                                       const HU wa[8][3],
                                       float& h0, float& h1, float& h2) {
    unsigned ua[8] = {qa0[0], qa0[1], qa0[2], qa0[3], qa1[0], qa1[1], qa1[2], qa1[3]};
    unsigned ub[8] = {qb0[0], qb0[1], qb0[2], qb0[3], qb1[0], qb1[1], qb1[2], qb1[3]};
    h0 = 0.f; h1 = 0.f; h2 = 0.f;
    #pragma unroll
    for (int k = 0; k < 8; ++k) {
        HU a, b, d;
        a.u = ua[k]; b.u = ub[k];
        d.h = a.h - b.h;
        d.u &= 0x7fff7fffu;               // packed abs
        h0 = __builtin_amdgcn_fdot2(d.h, wa[k][0].h, h0, false);
        h1 = __builtin_amdgcn_fdot2(d.h, wa[k][1].h, h1, false);
        h2 = __builtin_amdgcn_fdot2(d.h, wa[k][2].h, h2, false);
    }
}

// Main: bid = ((bi*16 + k) << 3) | bj. XCD = bj (j-slice 1.6 MB L2-resident); an XCD
// sweeps k=0..15 within one bi phase -> i-slice 0.8 MB also resident (2.4 MB < 4 MB L2,
// headroom for su/inv streams; r5's 8-bi split was 3.2 MB, no headroom).
// Body = r5's MLP-8 pipeline verbatim (q-hoist + next-iter row prefetch, VGPR~48):
// r7 proved the low-VGPR simple body serializes gathers (28 VGPR -> 94 us).
__global__ __launch_bounds__(256, 4) void adj_kernel_sorted(
    const unsigned* __restrict__ xh,
    unsigned* su,                       // in: j|i<<16 per slot; out: w (float bits)
    const int* __restrict__ cur,
    const unsigned* __restrict__ wah,
    const float* __restrict__ ba,
    const float* __restrict__ Wb,
    const float* __restrict__ bb)
{
    const int p    = blockIdx.y;
    const int bj   = blockIdx.x & 7;
    const int k    = (blockIdx.x >> 3) & 15;
    const int bi   = blockIdx.x >> 7;
    const int sb   = bj * 16 + bi;
    const int tid  = threadIdx.x;
    const int lane = tid & 63;
    const int wave = tid >> 6;
    const int sub  = lane & 7;
    const int grp  = lane >> 3;

    const int count = cur[p * NB + sb];
    const int base  = k * EDGES_PER_BLK;
    if (base >= count) return;

    HU wa[8][3];
    {
        const unsigned* wp = wah + ((size_t)p * 64 + sub * 8) * 3;
        #pragma unroll
        for (int kk = 0; kk < 8; ++kk) {
            wa[kk][0].u = wp[kk * 3 + 0];
            wa[kk][1].u = wp[kk * 3 + 1];
            wa[kk][2].u = wp[kk * 3 + 2];
        }
        #pragma unroll
        for (int kk = 0; kk < 8; ++kk) {
            asm volatile("" : "+v"(wa[kk][0].u), "+v"(wa[kk][1].u), "+v"(wa[kk][2].u));
        }
    }

    const float ba0 = ba[p * 3 + 0], ba1 = ba[p * 3 + 1], ba2 = ba[p * 3 + 2];
    const float wb0 = Wb[p * 3 + 0], wb1 = Wb[p * 3 + 1], wb2 = Wb[p * 3 + 2];
    const float bbp = bb[p];

    unsigned* sup = su + (size_t)(p * NB + sb) * CAPB;

    const int eoff = wave * 8 + grp;
    const int roff = sub * 8;
    const int cm1  = count - 1;

    // prologue: all 10 su loads issue immediately (independent addresses)
    unsigned q[2 * PAIRS];
    #pragma unroll
    for (int it = 0; it < PAIRS; ++it) {
        const int r1 = base + it * 64 + eoff;
        q[2 * it]     = __builtin_nontemporal_load(sup + min(r1, cm1));
        q[2 * it + 1] = __builtin_nontemporal_load(sup + min(r1 + 32, cm1));
    }

    u32x4 A0, A1, B0, B1, C0, C1, D0, D1;
    {
        const int j1 = (int)(q[0] & 0xFFFFu), i1 = (int)(q[0] >> 16);
        const int j2 = (int)(q[1] & 0xFFFFu), i2 = (int)(q[1] >> 16);
        const u32x4* rj1 = (const u32x4*)(xh + ((size_t)j1 << 6) + roff);
        const u32x4* ri1 = (const u32x4*)(xh + ((size_t)i1 << 6) + roff);
        const u32x4* rj2 = (const u32x4*)(xh + ((size_t)j2 << 6) + roff);
        const u32x4* ri2 = (const u32x4*)(xh + ((size_t)i2 << 6) + roff);
        A0 = rj1[0]; A1 = rj1[1]; B0 = ri1[0]; B1 = ri1[1];
        C0 = rj2[0]; C1 = rj2[1]; D0 = ri2[0]; D1 = ri2[1];
    }

    #pragma unroll
    for (int it = 0; it < PAIRS; ++it) {
        u32x4 nA0, nA1, nB0, nB1, nC0, nC1, nD0, nD1;
        if (it + 1 < PAIRS) {
            const int j1 = (int)(q[2 * it + 2] & 0xFFFFu), i1 = (int)(q[2 * it + 2] >> 16);
            const int j2 = (int)(q[2 * it + 3] & 0xFFFFu), i2 = (int)(q[2 * it + 3] >> 16);
            const u32x4* rj1 = (const u32x4*)(xh + ((size_t)j1 << 6) + roff);
            const u32x4* ri1 = (const u32x4*)(xh + ((size_t)i1 << 6) + roff);
            const u32x4* rj2 = (const u32x4*)(xh + ((size_t)j2 << 6) + roff);
            const u32x4* ri2 = (const u32x4*)(xh + ((size_t)i2 << 6) + roff);
            nA0 = rj1[0]; nA1 = rj1[1]; nB0 = ri1[0]; nB1 = ri1[1];
            nC0 = rj2[0]; nC1 = rj2[1]; nD0 = ri2[0]; nD1 = ri2[1];
        }

        float h0a, h1a, h2a, h0b, h1b, h2b;
        dot3_8(A0, A1, B0, B1, wa, h0a, h1a, h2a);
        dot3_8(C0, C1, D0, D1, wa, h0b, h1b, h2b);

        h0a += swz<0x041F>(h0a); h1a += swz<0x041F>(h1a); h2a += swz<0x041F>(h2a);
        h0b += swz<0x041F>(h0b); h1b += swz<0x041F>(h1b); h2b += swz<0x041F>(h2b);
        h0a += swz<0x081F>(h0a); h1a += swz<0x081F>(h1a); h2a += swz<0x081F>(h2a);
        h0b += swz<0x081F>(h0b); h1b += swz<0x081F>(h1b); h2b += swz<0x081F>(h2b);
        h0a += swz<0x101F>(h0a); h1a += swz<0x101F>(h1a); h2a += swz<0x101F>(h2a);
        h0b += swz<0x101F>(h0b); h1b += swz<0x101F>(h1b); h2b += swz<0x101F>(h2b);

        if (sub == 0) {
            const int r1 = base + it * 64 + eoff;
            const int r2 = r1 + 32;
            if (r1 < count) {
                float r0  = fmaxf(h0a + ba0, 0.f);
                float r1f = fmaxf(h1a + ba1, 0.f);
                float r2f = fmaxf(h2a + ba2, 0.f);
                float s   = fmaf(r0, wb0, fmaf(r1f, wb1, fmaf(r2f, wb2, bbp)));
                ((float*)sup)[r1] = 1.f / (1.f + __expf(-s));
            }
            if (r2 < count) {
                float r0  = fmaxf(h0b + ba0, 0.f);
                float r1f = fmaxf(h1b + ba1, 0.f);
                float r2f = fmaxf(h2b + ba2, 0.f);
                float s   = fmaf(r0, wb0, fmaf(r1f, wb1, fmaf(r2f, wb2, bbp)));
                ((float*)sup)[r2] = 1.f / (1.f + __expf(-s));
            }
        }

        if (it + 1 < PAIRS) {
            A0 = nA0; A1 = nA1; B0 = nB0; B1 = nB1;
            C0 = nC0; C1 = nC1; D0 = nD0; D1 = nD1;
        }
    }
}

// ---- final: out[e] = w[inv[e]] ; coalesced inv read + out write, L2/L3-warm gather ----
__global__ __launch_bounds__(256) void unscatter_kernel(const unsigned* __restrict__ su,
                                                        const int* __restrict__ inv,
                                                        float* __restrict__ out) {
    const int p  = blockIdx.y;
    const int t4 = (blockIdx.x * 256 + threadIdx.x) * 4;
    if (t4 >= N_EDGES) return;
    const int4 iv = *(const int4*)(inv + (size_t)p * N_EDGES + t4);
    const float* w = (const float*)su;          // inv holds GLOBAL slot indices
    float4 o;
    o.x = w[iv.x]; o.y = w[iv.y]; o.z = w[iv.z]; o.w = w[iv.w];
    __builtin_nontemporal_store(o.x, out + (size_t)p * N_EDGES + t4 + 0);
    __builtin_nontemporal_store(o.y, out + (size_t)p * N_EDGES + t4 + 1);
    __builtin_nontemporal_store(o.z, out + (size_t)p * N_EDGES + t4 + 2);
    __builtin_nontemporal_store(o.w, out + (size_t)p * N_EDGES + t4 + 3);
}

// ---- round-4 path (no sorting) for mid-size ws ----
__global__ __launch_bounds__(256) void adj_kernel_f16(
    const unsigned* __restrict__ xh,
    const unsigned* __restrict__ wah,
    const int*   __restrict__ edge_index,
    const float* __restrict__ ba,
    const float* __restrict__ Wb,
    const float* __restrict__ bb,
    float* __restrict__ out)
{
    const int p    = blockIdx.y;
    const int tid  = threadIdx.x;
    const int lane = tid & 63;
    const int wave = tid >> 6;
    const int sub  = lane & 7;
    const int grp  = lane >> 3;

    HU wa[8][3];
    {
        const unsigned* wp = wah + ((size_t)p * 64 + sub * 8) * 3;
        #pragma unroll
        for (int k = 0; k < 8; ++k) {
            wa[k][0].u = wp[k * 3 + 0];
            wa[k][1].u = wp[k * 3 + 1];
            wa[k][2].u = wp[k * 3 + 2];
        }
        #pragma unroll
        for (int k = 0; k < 8; ++k) {
            asm volatile("" : "+v"(wa[k][0].u), "+v"(wa[k][1].u), "+v"(wa[k][2].u));
        }
    }

    const float ba0 = ba[p * 3 + 0], ba1 = ba[p * 3 + 1], ba2 = ba[p * 3 + 2];
    const float wb0 = Wb[p * 3 + 0], wb1 = Wb[p * 3 + 1], wb2 = Wb[p * 3 + 2];
    const float bbp = bb[p];

    const int* ej = edge_index + (size_t)p * 2 * N_EDGES;
    const int* ei = ej + N_EDGES;
    float* outp = out + (size_t)p * N_EDGES;

    const int e_blk = blockIdx.x * EDGES_PER_BLK;
    const int eoff  = wave * 8 + grp;
    const int roff  = sub * 8;

    #pragma unroll
    for (int it = 0; it < PAIRS; ++it) {
        const int e1 = e_blk + it * 64 + eoff;
        const int e2 = e1 + 32;
        const int j1 = __builtin_nontemporal_load(ej + e1);
        const int i1 = __builtin_nontemporal_load(ei + e1);
        const int j2 = __builtin_nontemporal_load(ej + e2);
        const int i2 = __builtin_nontemporal_load(ei + e2);

        const u32x4* rj1 = (const u32x4*)(xh + ((size_t)j1 << 6) + roff);
        const u32x4* ri1 = (const u32x4*)(xh + ((size_t)i1 << 6) + roff);
        const u32x4* rj2 = (const u32x4*)(xh + ((size_t)j2 << 6) + roff);
        const u32x4* ri2 = (const u32x4*)(xh + ((size_t)i2 << 6) + roff);
        u32x4 a0 = rj1[0], a1 = rj1[1];
        u32x4 b0 = ri1[0], b1 = ri1[1];
        u32x4 c0 = rj2[0], c1 = rj2[1];
        u32x4 d0 = ri2[0], d1 = ri2[1];

        float h0a, h1a, h2a, h0b, h1b, h2b;
        dot3_8(a0, a1, b0, b1, wa, h0a, h1a, h2a);
        dot3_8(c0, c1, d0, d1, wa, h0b, h1b, h2b);

        h0a += swz<0x041F>(h0a); h1a += swz<0x041F>(h1a); h2a += swz<0x041F>(h2a);
        h0b += swz<0x041F>(h0b); h1b += swz<0x041F>(h1b); h2b += swz<0x041F>(h2b);
        h0a += swz<0x081F>(h0a); h1a += swz<0x081F>(h1a); h2a += swz<0x081F>(h2a);
        h0b += swz<0x081F>(h0b); h1b += swz<0x081F>(h1b); h2b += swz<0x081F>(h2b);
        h0a += swz<0x101F>(h0a); h1a += swz<0x101F>(h1a); h2a += swz<0x101F>(h2a);
        h0b += swz<0x101F>(h0b); h1b += swz<0x101F>(h1b); h2b += swz<0x101F>(h2b);

        if (sub == 0) {
            float r0 = fmaxf(h0a + ba0, 0.f);
            float r1 = fmaxf(h1a + ba1, 0.f);
            float r2 = fmaxf(h2a + ba2, 0.f);
            float s  = fmaf(r0, wb0, fmaf(r1, wb1, fmaf(r2, wb2, bbp)));
            __builtin_nontemporal_store(1.f / (1.f + __expf(-s)), outp + e1);
            r0 = fmaxf(h0b + ba0, 0.f);
            r1 = fmaxf(h1b + ba1, 0.f);
            r2 = fmaxf(h2b + ba2, 0.f);
            s  = fmaf(r0, wb0, fmaf(r1, wb1, fmaf(r2, wb2, bbp)));
            __builtin_nontemporal_store(1.f / (1.f + __expf(-s)), outp + e2);
        }
    }
}

// ---- fp32 fallback (no workspace) ----
__global__ __launch_bounds__(256) void adj_kernel_f32(
    const float* __restrict__ x,
    const int*   __restrict__ edge_index,
    const float* __restrict__ Wa,
    const float* __restrict__ ba,
    const float* __restrict__ Wb,
    const float* __restrict__ bb,
    float* __restrict__ out)
{
    const int p    = blockIdx.y;
    const int tid  = threadIdx.x;
    const int lane = tid & 63;
    const int wave = tid >> 6;
    const int sub  = lane & 15;
    const int grp  = lane >> 4;
    const int f0 = sub * 8;

    const float* Wap = Wa + (size_t)p * N_FEAT * 3;
    float wa0[8], wa1[8], wa2[8];
    #pragma unroll
    for (int k = 0; k < 8; ++k) {
        wa0[k] = Wap[(f0 + k) * 3 + 0];
        wa1[k] = Wap[(f0 + k) * 3 + 1];
        wa2[k] = Wap[(f0 + k) * 3 + 2];
    }
    const float ba0 = ba[p * 3 + 0], ba1 = ba[p * 3 + 1], ba2 = ba[p * 3 + 2];
    const float wb0 = Wb[p * 3 + 0], wb1 = Wb[p * 3 + 1], wb2 = Wb[p * 3 + 2];
    const float bbp = bb[p];

    const int e = blockIdx.x * 16 + wave * 4 + grp;
    const int* ej = edge_index + (size_t)p * 2 * N_EDGES;
    const int* ei = ej + N_EDGES;
    const int j = ej[e];
    const int i = ei[e];

    const float4* xj = (const float4*)(x + (size_t)j * N_FEAT + f0);
    const float4* xi = (const float4*)(x + (size_t)i * N_FEAT + f0);
    float4 a0 = xj[0], a1 = xj[1];
    float4 b0 = xi[0], b1 = xi[1];

    float d[8];
    d[0] = fabsf(a0.x - b0.x); d[1] = fabsf(a0.y - b0.y);
    d[2] = fabsf(a0.z - b0.z); d[3] = fabsf(a0.w - b0.w);
    d[4] = fabsf(a1.x - b1.x); d[5] = fabsf(a1.y - b1.y);
    d[6] = fabsf(a1.z - b1.z); d[7] = fabsf(a1.w - b1.w);

    float h0 = 0.f, h1 = 0.f, h2 = 0.f;
    #pragma unroll
    for (int k = 0; k < 8; ++k) {
        h0 = fmaf(d[k], wa0[k], h0);
        h1 = fmaf(d[k], wa1[k], h1);
        h2 = fmaf(d[k], wa2[k], h2);
    }
    #pragma unroll
    for (int m = 1; m < 16; m <<= 1) {
        h0 += __shfl_xor(h0, m, 64);
        h1 += __shfl_xor(h1, m, 64);
        h2 += __shfl_xor(h2, m, 64);
    }
    if (sub == 0) {
        float r0 = fmaxf(h0 + ba0, 0.f);
        float r1 = fmaxf(h1 + ba1, 0.f);
        float r2 = fmaxf(h2 + ba2, 0.f);
        float s  = fmaf(r0, wb0, fmaf(r1, wb1, fmaf(r2, wb2, bbp)));
        float w  = 1.f / (1.f + expf(-s));
        out[(size_t)p * N_EDGES + e] = w;
    }
}

extern "C" void kernel_launch(void* const* d_in, const int* in_sizes, int n_in,
                              void* d_out, int out_size, void* d_ws, size_t ws_size,
                              hipStream_t stream) {
    const float* x          = (const float*)d_in[0];
    const int*   edge_index = (const int*)d_in[1];
    const float* Wa         = (const float*)d_in[2];
    const float* ba         = (const float*)d_in[3];
    const float* Wb         = (const float*)d_in[4];
    const float* bb         = (const float*)d_in[5];
    float* out = (float*)d_out;

    const size_t x_bytes   = (size_t)N_NODES * N_FEAT * 2;          // 12,800,000
    const size_t su_bytes  = (size_t)N_POWERS * NB * CAPB * 4;      //  7,864,320
    const size_t inv_bytes = (size_t)N_POWERS * N_EDGES * 4;        //  7,200,000
    const size_t wa_bytes  = 2304;
    const size_t cur_bytes = N_POWERS * NB * 4;                     //      1,536
    const size_t need_full = x_bytes + su_bytes + inv_bytes + wa_bytes + cur_bytes;

    if (ws_size >= need_full) {
        char* w = (char*)d_ws;
        unsigned* xh  = (unsigned*)w;
        unsigned* su  = (unsigned*)(w + x_bytes);
        int*      inv = (int*)(w + x_bytes + su_bytes);
        unsigned* wah = (unsigned*)(w + x_bytes + su_bytes + inv_bytes);
        int*      cur = (int*)(w + x_bytes + su_bytes + inv_bytes + wa_bytes);

        conv_x_plain<<<N_NODES * N_FEAT / 2048, 256, 0, stream>>>(x, xh, Wa, wah, cur);
        scatter_onepass<<<dim3(NCHUNK, N_POWERS), 256, 0, stream>>>(edge_index, su, inv, cur);
        dim3 grid(NB * (CAPB / EDGES_PER_BLK), N_POWERS);   // (2048, 3)
        adj_kernel_sorted<<<grid, 256, 0, stream>>>(xh, su, cur, wah, ba, Wb, bb);
        unscatter_kernel<<<dim3((N_EDGES / 4 + 255) / 256, N_POWERS), 256, 0, stream>>>(
            su, inv, out);
    } else if (ws_size >= x_bytes + wa_bytes) {
        unsigned* xh  = (unsigned*)d_ws;
        unsigned* wah = (unsigned*)((char*)d_ws + x_bytes);
        conv_x_plain<<<N_NODES * N_FEAT / 2048, 256, 0, stream>>>(x, xh, Wa, wah, nullptr);
        dim3 grid(N_EDGES / EDGES_PER_BLK, N_POWERS);
        adj_kernel_f16<<<grid, 256, 0, stream>>>(xh, wah, edge_index, ba, Wb, bb, out);
    } else {
        dim3 grid((N_EDGES + 15) / 16, N_POWERS);
        adj_kernel_f32<<<grid, 256, 0, stream>>>(x, edge_index, Wa, ba, Wb, bb, out);
    }
}

// Round 10
// 174.622 us; speedup vs baseline: 1.5218x; 1.0003x over previous
//
#include <hip/hip_runtime.h>
#include <math.h>

#define N_NODES 50000
#define N_FEAT  128
#define N_EDGES 600000
#define N_POWERS 3

#define PAIRS 5
#define EDGES_PER_BLK (64 * PAIRS)   // 320

#define NB 128                       // (j,i) pair buckets: (j/6250)*16 + i/3125
#define CAPB 5120                    // per-bucket capacity (mean 4688, +6.3 sigma)
#define CHUNK 2048
#define NCHUNK 293                   // ceil(600000 / 2048)

typedef _Float16 half2v __attribute__((ext_vector_type(2)));
typedef unsigned u32x4  __attribute__((ext_vector_type(4)));
union HU { unsigned u; half2v h; };

// ---- conversion: x fp32 -> packed f16 rows; block 0 packs Wa; block 1 zeroes cur ----
__global__ __launch_bounds__(256) void conv_x_plain(const float* __restrict__ x,
                                                    unsigned* __restrict__ xh,
                                                    const float* __restrict__ Wa,
                                                    unsigned* __restrict__ wah,
                                                    int* __restrict__ cur) {
    const int t = blockIdx.x * 256 + threadIdx.x;   // 800000 threads exactly
    const float4* x4 = (const float4*)x;
    float4 a = x4[(size_t)t * 2];
    float4 b = x4[(size_t)t * 2 + 1];
    HU p0, p1, p2, p3;
    p0.h = half2v{(_Float16)a.x, (_Float16)a.y};
    p1.h = half2v{(_Float16)a.z, (_Float16)a.w};
    p2.h = half2v{(_Float16)b.x, (_Float16)b.y};
    p3.h = half2v{(_Float16)b.z, (_Float16)b.w};
    ((uint4*)xh)[t] = uint4{p0.u, p1.u, p2.u, p3.u};
    if (blockIdx.x == 0 && threadIdx.x < 192) {
        const int tt = threadIdx.x;
        #pragma unroll
        for (int q = 0; q < 3; ++q) {
            int idx = tt + q * 192;            // 576 entries: (p,k,c)
            int c  = idx % 3;
            int pk = idx / 3;
            int k  = pk % 64;
            int p  = pk / 64;
            float w0 = Wa[p * 384 + (2 * k) * 3 + c];
            float w1 = Wa[p * 384 + (2 * k + 1) * 3 + c];
            HU u; u.h = half2v{(_Float16)w0, (_Float16)w1};
            wah[idx] = u.u;
        }
    }
    if (cur != nullptr && blockIdx.x == 1)
        for (int tt = threadIdx.x; tt < N_POWERS * NB; tt += 256)
            cur[tt] = 0;
}

// ---- single-pass 128-bucket binning: 7-ballot ranking + 2-wave shfl scan ----
// LDS-staged so ALL su writes are coalesced (scattered partial-line writes cost ~8-16x:
// cross-XCD line bounce, r4 evidence). Emits inv[e]=global slot in e-order (coalesced).
// r10: Hillis-Steele scan (14 barriers) replaced by 2-wave shfl_up scan (2 barriers).
__global__ __launch_bounds__(256) void scatter_onepass(const int* __restrict__ edge_index,
                                                       unsigned* __restrict__ su,
                                                       int* __restrict__ inv,
                                                       int* __restrict__ cur) {
    __shared__ int tot[4][NB];
    __shared__ int sh_w[4][NB];
    __shared__ int sh_lbase[NB];
    __shared__ int sh_delta[NB];
    __shared__ int sh_half;
    __shared__ int sh_vt;
    __shared__ unsigned pay[CHUNK];
    __shared__ int dlt[CHUNK];

    const int p = blockIdx.y, chunk = blockIdx.x;
    const int tid  = threadIdx.x;
    const int lane = tid & 63;
    const int wave = tid >> 6;
    const int* ej = edge_index + (size_t)p * 2 * N_EDGES;
    const int* ei = ej + N_EDGES;
    const int base = chunk * CHUNK;

    int jj[8], ii[8], sbk[8], off[8];
    int runA = 0, runB = 0;            // lane L tracks buckets L and L+64
    #pragma unroll
    for (int k = 0; k < 8; ++k) {
        const int e = base + k * 256 + tid;
        const bool valid = e < N_EDGES;
        jj[k] = __builtin_nontemporal_load(ej + (valid ? e : 0));
        ii[k] = __builtin_nontemporal_load(ei + (valid ? e : 0));
        const int b = (jj[k] / 6250) * 16 + (ii[k] / 3125);
        sbk[k] = b;
        const unsigned long long m0 = __ballot(b & 1);
        const unsigned long long m1 = __ballot(b & 2);
        const unsigned long long m2 = __ballot(b & 4);
        const unsigned long long m3 = __ballot(b & 8);
        const unsigned long long m4 = __ballot(b & 16);
        const unsigned long long m5 = __ballot(b & 32);
        const unsigned long long m6 = __ballot(b & 64);
        const unsigned long long vm = __ballot(valid);
        unsigned long long m = ((b & 1) ? m0 : ~m0);
        m &= ((b & 2)  ? m1 : ~m1);
        m &= ((b & 4)  ? m2 : ~m2);
        m &= ((b & 8)  ? m3 : ~m3);
        m &= ((b & 16) ? m4 : ~m4);
        m &= ((b & 32) ? m5 : ~m5);
        m &= ((b & 64) ? m6 : ~m6);
        m &= vm;
        const int rank = (int)__popcll(m & ((1ull << lane) - 1ull));
        // masks for buckets (lane) and (lane+64): bits 0..5 match lane, bit 6 selects
        unsigned long long cm = ((lane & 1) ? m0 : ~m0);
        cm &= ((lane & 2)  ? m1 : ~m1);
        cm &= ((lane & 4)  ? m2 : ~m2);
        cm &= ((lane & 8)  ? m3 : ~m3);
        cm &= ((lane & 16) ? m4 : ~m4);
        cm &= ((lane & 32) ? m5 : ~m5);
        cm &= vm;
        const int cntA = (int)__popcll(cm & ~m6);
        const int cntB = (int)__popcll(cm & m6);
        const int preA = __shfl(runA, b & 63, 64);
        const int preB = __shfl(runB, b & 63, 64);
        off[k] = ((b & 64) ? preB : preA) + rank;
        runA += cntA; runB += cntB;
    }
    tot[wave][lane]      = runA;
    tot[wave][lane + 64] = runB;
    __syncthreads();

    // 2-wave shfl scan over 128 buckets: wave 0 owns [0,64), wave 1 owns [64,128)
    int bt = 0, incl = 0;
    if (tid < NB) {
        const int t0 = tot[0][tid], t1 = tot[1][tid], t2 = tot[2][tid], t3 = tot[3][tid];
        bt = t0 + t1 + t2 + t3;
        sh_w[0][tid] = 0;
        sh_w[1][tid] = t0;
        sh_w[2][tid] = t0 + t1;
        sh_w[3][tid] = t0 + t1 + t2;
        incl = bt;
        #pragma unroll
        for (int d = 1; d < 64; d <<= 1) {
            int u = __shfl_up(incl, d, 64);
            if (lane >= d) incl += u;
        }
        if (tid == 63) sh_half = incl;          // total of buckets [0,64)
    }
    __syncthreads();
    if (tid < NB) {
        if (tid >= 64) incl += sh_half;
        const int lb = incl - bt;               // LDS packing base for this bucket
        const int g  = atomicAdd(&cur[p * NB + tid], bt);
        sh_lbase[tid] = lb;
        sh_delta[tid] = (p * NB + tid) * CAPB + g - lb;   // global slot = delta + pos
        if (tid == NB - 1) sh_vt = lb + bt;
    }
    __syncthreads();

    #pragma unroll
    for (int k = 0; k < 8; ++k) {               // pack bucket-contiguous into LDS
        const int e = base + k * 256 + tid;
        if (e < N_EDGES) {
            const int b = sbk[k];
            const int pos = sh_lbase[b] + sh_w[wave][b] + off[k];
            pay[pos] = (unsigned)(jj[k] | (ii[k] << 16));
            dlt[pos] = sh_delta[b];
            inv[(size_t)p * N_EDGES + e] = sh_delta[b] + pos;   // coalesced (e-order)
        }
    }
    __syncthreads();

    const int vt = sh_vt;                       // coalesced flush (runs of ~16 slots)
    #pragma unroll
    for (int k = 0; k < 8; ++k) {
        const int pos = k * 256 + tid;
        if (pos < vt)
            su[(size_t)(dlt[pos] + pos)] = pay[pos];
    }
}

template<int PAT>
__device__ __forceinline__ float swz(float v) {
    return __int_as_float(__builtin_amdgcn_ds_swizzle(__float_as_int(v), PAT));
}

__device__ __forceinline__ void dot3_8(const u32x4& qa0, const u32x4& qa1,
                                       const u32x4& qb0, const u32x4& qb1,
                                       const HU wa[8][3],
                                       float& h0, float& h1, float& h2) {
    unsigned ua[8] = {qa0[0], qa0[1], qa0[2], qa0[3], qa1[0], qa1[1], qa1[2], qa1[3]};
    unsigned ub[8] = {qb0[0], qb0[1], qb0[2], qb0[3], qb1[0], qb1[1], qb1[2], qb1[3]};
    h0 = 0.f; h1 = 0.f; h2 = 0.f;
    #pragma unroll
    for (int k = 0; k < 8; ++k) {
        HU a, b, d;
        a.u = ua[k]; b.u = ub[k];
        d.h = a.h - b.h;
        d.u &= 0x7fff7fffu;               // packed abs
        h0 = __builtin_amdgcn_fdot2(d.h, wa[k][0].h, h0, false);
        h1 = __builtin_amdgcn_fdot2(d.h, wa[k][1].h, h1, false);
        h2 = __builtin_amdgcn_fdot2(d.h, wa[k][2].h, h2, false);
    }
}

// Main: bid = ((bi*16 + k) << 3) | bj. XCD = bj (j-slice 1.6 MB L2-resident); an XCD
// sweeps k=0..15 within one bi phase -> i-slice 0.8 MB also resident.
// Body = r5's MLP-8 pipeline verbatim (q-hoist + next-iter row prefetch, VGPR~52):
// r7 proved the low-VGPR simple body serializes gathers (28 VGPR -> 94 us).
// Best measured config of the session: 62.0 us, FETCH 135 MB, WRITE 7.1 MB (r9).
__global__ __launch_bounds__(256, 4) void adj_kernel_sorted(
    const unsigned* __restrict__ xh,
    unsigned* su,                       // in: j|i<<16 per slot; out: w (float bits)
    const int* __restrict__ cur,
    const unsigned* __restrict__ wah,
    const float* __restrict__ ba,
    const float* __restrict__ Wb,
    const float* __restrict__ bb)
{
    const int p    = blockIdx.y;
    const int bj   = blockIdx.x & 7;
    const int k    = (blockIdx.x >> 3) & 15;
    const int bi   = blockIdx.x >> 7;
    const int sb   = bj * 16 + bi;
    const int tid  = threadIdx.x;
    const int lane = tid & 63;
    const int wave = tid >> 6;
    const int sub  = lane & 7;
    const int grp  = lane >> 3;

    const int count = cur[p * NB + sb];
    const int base  = k * EDGES_PER_BLK;
    if (base >= count) return;

    HU wa[8][3];
    {
        const unsigned* wp = wah + ((size_t)p * 64 + sub * 8) * 3;
        #pragma unroll
        for (int kk = 0; kk < 8; ++kk) {
            wa[kk][0].u = wp[kk * 3 + 0];
            wa[kk][1].u = wp[kk * 3 + 1];
            wa[kk][2].u = wp[kk * 3 + 2];
        }
        #pragma unroll
        for (int kk = 0; kk < 8; ++kk) {
            asm volatile("" : "+v"(wa[kk][0].u), "+v"(wa[kk][1].u), "+v"(wa[kk][2].u));
        }
    }

    const float ba0 = ba[p * 3 + 0], ba1 = ba[p * 3 + 1], ba2 = ba[p * 3 + 2];
    const float wb0 = Wb[p * 3 + 0], wb1 = Wb[p * 3 + 1], wb2 = Wb[p * 3 + 2];
    const float bbp = bb[p];

    unsigned* sup = su + (size_t)(p * NB + sb) * CAPB;

    const int eoff = wave * 8 + grp;
    const int roff = sub * 8;
    const int cm1  = count - 1;

    // prologue: all 10 su loads issue immediately (independent addresses)
    unsigned q[2 * PAIRS];
    #pragma unroll
    for (int it = 0; it < PAIRS; ++it) {
        const int r1 = base + it * 64 + eoff;
        q[2 * it]     = __builtin_nontemporal_load(sup + min(r1, cm1));
        q[2 * it + 1] = __builtin_nontemporal_load(sup + min(r1 + 32, cm1));
    }

    u32x4 A0, A1, B0, B1, C0, C1, D0, D1;
    {
        const int j1 = (int)(q[0] & 0xFFFFu), i1 = (int)(q[0] >> 16);
        const int j2 = (int)(q[1] & 0xFFFFu), i2 = (int)(q[1] >> 16);
        const u32x4* rj1 = (const u32x4*)(xh + ((size_t)j1 << 6) + roff);
        const u32x4* ri1 = (const u32x4*)(xh + ((size_t)i1 << 6) + roff);
        const u32x4* rj2 = (const u32x4*)(xh + ((size_t)j2 << 6) + roff);
        const u32x4* ri2 = (const u32x4*)(xh + ((size_t)i2 << 6) + roff);
        A0 = rj1[0]; A1 = rj1[1]; B0 = ri1[0]; B1 = ri1[1];
        C0 = rj2[0]; C1 = rj2[1]; D0 = ri2[0]; D1 = ri2[1];
    }

    #pragma unroll
    for (int it = 0; it < PAIRS; ++it) {
        u32x4 nA0, nA1, nB0, nB1, nC0, nC1, nD0, nD1;
        if (it + 1 < PAIRS) {
            const int j1 = (int)(q[2 * it + 2] & 0xFFFFu), i1 = (int)(q[2 * it + 2] >> 16);
            const int j2 = (int)(q[2 * it + 3] & 0xFFFFu), i2 = (int)(q[2 * it + 3] >> 16);
            const u32x4* rj1 = (const u32x4*)(xh + ((size_t)j1 << 6) + roff);
            const u32x4* ri1 = (const u32x4*)(xh + ((size_t)i1 << 6) + roff);
            const u32x4* rj2 = (const u32x4*)(xh + ((size_t)j2 << 6) + roff);
            const u32x4* ri2 = (const u32x4*)(xh + ((size_t)i2 << 6) + roff);
            nA0 = rj1[0]; nA1 = rj1[1]; nB0 = ri1[0]; nB1 = ri1[1];
            nC0 = rj2[0]; nC1 = rj2[1]; nD0 = ri2[0]; nD1 = ri2[1];
        }

        float h0a, h1a, h2a, h0b, h1b, h2b;
        dot3_8(A0, A1, B0, B1, wa, h0a, h1a, h2a);
        dot3_8(C0, C1, D0, D1, wa, h0b, h1b, h2b);

        h0a += swz<0x041F>(h0a); h1a += swz<0x041F>(h1a); h2a += swz<0x041F>(h2a);
        h0b += swz<0x041F>(h0b); h1b += swz<0x041F>(h1b); h2b += swz<0x041F>(h2b);
        h0a += swz<0x081F>(h0a); h1a += swz<0x081F>(h1a); h2a += swz<0x081F>(h2a);
        h0b += swz<0x081F>(h0b); h1b += swz<0x081F>(h1b); h2b += swz<0x081F>(h2b);
        h0a += swz<0x101F>(h0a); h1a += swz<0x101F>(h1a); h2a += swz<0x101F>(h2a);
        h0b += swz<0x101F>(h0b); h1b += swz<0x101F>(h1b); h2b += swz<0x101F>(h2b);

        if (sub == 0) {
            const int r1 = base + it * 64 + eoff;
            const int r2 = r1 + 32;
            if (r1 < count) {
                float r0  = fmaxf(h0a + ba0, 0.f);
                float r1f = fmaxf(h1a + ba1, 0.f);
                float r2f = fmaxf(h2a + ba2, 0.f);
                float s   = fmaf(r0, wb0, fmaf(r1f, wb1, fmaf(r2f, wb2, bbp)));
                ((float*)sup)[r1] = 1.f / (1.f + __expf(-s));
            }
            if (r2 < count) {
                float r0  = fmaxf(h0b + ba0, 0.f);
                float r1f = fmaxf(h1b + ba1, 0.f);
                float r2f = fmaxf(h2b + ba2, 0.f);
                float s   = fmaf(r0, wb0, fmaf(r1f, wb1, fmaf(r2f, wb2, bbp)));
                ((float*)sup)[r2] = 1.f / (1.f + __expf(-s));
            }
        }

        if (it + 1 < PAIRS) {
            A0 = nA0; A1 = nA1; B0 = nB0; B1 = nB1;
            C0 = nC0; C1 = nC1; D0 = nD0; D1 = nD1;
        }
    }
}

// ---- final: out[e] = w[inv[e]] ; coalesced inv read + out write, L2/L3-warm gather ----
__global__ __launch_bounds__(256) void unscatter_kernel(const unsigned* __restrict__ su,
                                                        const int* __restrict__ inv,
                                                        float* __restrict__ out) {
    const int p  = blockIdx.y;
    const int t4 = (blockIdx.x * 256 + threadIdx.x) * 4;
    if (t4 >= N_EDGES) return;
    const int4 iv = *(const int4*)(inv + (size_t)p * N_EDGES + t4);
    const float* w = (const float*)su;          // inv holds GLOBAL slot indices
    float4 o;
    o.x = w[iv.x]; o.y = w[iv.y]; o.z = w[iv.z]; o.w = w[iv.w];
    __builtin_nontemporal_store(o.x, out + (size_t)p * N_EDGES + t4 + 0);
    __builtin_nontemporal_store(o.y, out + (size_t)p * N_EDGES + t4 + 1);
    __builtin_nontemporal_store(o.z, out + (size_t)p * N_EDGES + t4 + 2);
    __builtin_nontemporal_store(o.w, out + (size_t)p * N_EDGES + t4 + 3);
}

// ---- round-4 path (no sorting) for mid-size ws ----
__global__ __launch_bounds__(256) void adj_kernel_f16(
    const unsigned* __restrict__ xh,
    const unsigned* __restrict__ wah,
    const int*   __restrict__ edge_index,
    const float* __restrict__ ba,
    const float* __restrict__ Wb,
    const float* __restrict__ bb,
    float* __restrict__ out)
{
    const int p    = blockIdx.y;
    const int tid  = threadIdx.x;
    const int lane = tid & 63;
    const int wave = tid >> 6;
    const int sub  = lane & 7;
    const int grp  = lane >> 3;

    HU wa[8][3];
    {
        const unsigned* wp = wah + ((size_t)p * 64 + sub * 8) * 3;
        #pragma unroll
        for (int k = 0; k < 8; ++k) {
            wa[k][0].u = wp[k * 3 + 0];
            wa[k][1].u = wp[k * 3 + 1];
            wa[k][2].u = wp[k * 3 + 2];
        }
        #pragma unroll
        for (int k = 0; k < 8; ++k) {
            asm volatile("" : "+v"(wa[k][0].u), "+v"(wa[k][1].u), "+v"(wa[k][2].u));
        }
    }

    const float ba0 = ba[p * 3 + 0], ba1 = ba[p * 3 + 1], ba2 = ba[p * 3 + 2];
    const float wb0 = Wb[p * 3 + 0], wb1 = Wb[p * 3 + 1], wb2 = Wb[p * 3 + 2];
    const float bbp = bb[p];

    const int* ej = edge_index + (size_t)p * 2 * N_EDGES;
    const int* ei = ej + N_EDGES;
    float* outp = out + (size_t)p * N_EDGES;

    const int e_blk = blockIdx.x * EDGES_PER_BLK;
    const int eoff  = wave * 8 + grp;
    const int roff  = sub * 8;

    #pragma unroll
    for (int it = 0; it < PAIRS; ++it) {
        const int e1 = e_blk + it * 64 + eoff;
        const int e2 = e1 + 32;
        const int j1 = __builtin_nontemporal_load(ej + e1);
        const int i1 = __builtin_nontemporal_load(ei + e1);
        const int j2 = __builtin_nontemporal_load(ej + e2);
        const int i2 = __builtin_nontemporal_load(ei + e2);

        const u32x4* rj1 = (const u32x4*)(xh + ((size_t)j1 << 6) + roff);
        const u32x4* ri1 = (const u32x4*)(xh + ((size_t)i1 << 6) + roff);
        const u32x4* rj2 = (const u32x4*)(xh + ((size_t)j2 << 6) + roff);
        const u32x4* ri2 = (const u32x4*)(xh + ((size_t)i2 << 6) + roff);
        u32x4 a0 = rj1[0], a1 = rj1[1];
        u32x4 b0 = ri1[0], b1 = ri1[1];
        u32x4 c0 = rj2[0], c1 = rj2[1];
        u32x4 d0 = ri2[0], d1 = ri2[1];

        float h0a, h1a, h2a, h0b, h1b, h2b;
        dot3_8(a0, a1, b0, b1, wa, h0a, h1a, h2a);
        dot3_8(c0, c1, d0, d1, wa, h0b, h1b, h2b);

        h0a += swz<0x041F>(h0a); h1a += swz<0x041F>(h1a); h2a += swz<0x041F>(h2a);
        h0b += swz<0x041F>(h0b); h1b += swz<0x041F>(h1b); h2b += swz<0x041F>(h2b);
        h0a += swz<0x081F>(h0a); h1a += swz<0x081F>(h1a); h2a += swz<0x081F>(h2a);
        h0b += swz<0x081F>(h0b); h1b += swz<0x081F>(h1b); h2b += swz<0x081F>(h2b);
        h0a += swz<0x101F>(h0a); h1a += swz<0x101F>(h1a); h2a += swz<0x101F>(h2a);
        h0b += swz<0x101F>(h0b); h1b += swz<0x101F>(h1b); h2b += swz<0x101F>(h2b);

        if (sub == 0) {
            float r0 = fmaxf(h0a + ba0, 0.f);
            float r1 = fmaxf(h1a + ba1, 0.f);
            float r2 = fmaxf(h2a + ba2, 0.f);
            float s  = fmaf(r0, wb0, fmaf(r1, wb1, fmaf(r2, wb2, bbp)));
            __builtin_nontemporal_store(1.f / (1.f + __expf(-s)), outp + e1);
            r0 = fmaxf(h0b + ba0, 0.f);
            r1 = fmaxf(h1b + ba1, 0.f);
            r2 = fmaxf(h2b + ba2, 0.f);
            s  = fmaf(r0, wb0, fmaf(r1, wb1, fmaf(r2, wb2, bbp)));
            __builtin_nontemporal_store(1.f / (1.f + __expf(-s)), outp + e2);
        }
    }
}

// ---- fp32 fallback (no workspace) ----
__global__ __launch_bounds__(256) void adj_kernel_f32(
    const float* __restrict__ x,
    const int*   __restrict__ edge_index,
    const float* __restrict__ Wa,
    const float* __restrict__ ba,
    const float* __restrict__ Wb,
    const float* __restrict__ bb,
    float* __restrict__ out)
{
    const int p    = blockIdx.y;
    const int tid  = threadIdx.x;
    const int lane = tid & 63;
    const int wave = tid >> 6;
    const int sub  = lane & 15;
    const int grp  = lane >> 4;
    const int f0 = sub * 8;

    const float* Wap = Wa + (size_t)p * N_FEAT * 3;
    float wa0[8], wa1[8], wa2[8];
    #pragma unroll
    for (int k = 0; k < 8; ++k) {
        wa0[k] = Wap[(f0 + k) * 3 + 0];
        wa1[k] = Wap[(f0 + k) * 3 + 1];
        wa2[k] = Wap[(f0 + k) * 3 + 2];
    }
    const float ba0 = ba[p * 3 + 0], ba1 = ba[p * 3 + 1], ba2 = ba[p * 3 + 2];
    const float wb0 = Wb[p * 3 + 0], wb1 = Wb[p * 3 + 1], wb2 = Wb[p * 3 + 2];
    const float bbp = bb[p];

    const int e = blockIdx.x * 16 + wave * 4 + grp;
    const int* ej = edge_index + (size_t)p * 2 * N_EDGES;
    const int* ei = ej + N_EDGES;
    const int j = ej[e];
    const int i = ei[e];

    const float4* xj = (const float4*)(x + (size_t)j * N_FEAT + f0);
    const float4* xi = (const float4*)(x + (size_t)i * N_FEAT + f0);
    float4 a0 = xj[0], a1 = xj[1];
    float4 b0 = xi[0], b1 = xi[1];

    float d[8];
    d[0] = fabsf(a0.x - b0.x); d[1] = fabsf(a0.y - b0.y);
    d[2] = fabsf(a0.z - b0.z); d[3] = fabsf(a0.w - b0.w);
    d[4] = fabsf(a1.x - b1.x); d[5] = fabsf(a1.y - b1.y);
    d[6] = fabsf(a1.z - b1.z); d[7] = fabsf(a1.w - b1.w);

    float h0 = 0.f, h1 = 0.f, h2 = 0.f;
    #pragma unroll
    for (int k = 0; k < 8; ++k) {
        h0 = fmaf(d[k], wa0[k], h0);
        h1 = fmaf(d[k], wa1[k], h1);
        h2 = fmaf(d[k], wa2[k], h2);
    }
    #pragma unroll
    for (int m = 1; m < 16; m <<= 1) {
        h0 += __shfl_xor(h0, m, 64);
        h1 += __shfl_xor(h1, m, 64);
        h2 += __shfl_xor(h2, m, 64);
    }
    if (sub == 0) {
        float r0 = fmaxf(h0 + ba0, 0.f);
        float r1 = fmaxf(h1 + ba1, 0.f);
        float r2 = fmaxf(h2 + ba2, 0.f);
        float s  = fmaf(r0, wb0, fmaf(r1, wb1, fmaf(r2, wb2, bbp)));
        float w  = 1.f / (1.f + expf(-s));
        out[(size_t)p * N_EDGES + e] = w;
    }
}

extern "C" void kernel_launch(void* const* d_in, const int* in_sizes, int n_in,
                              void* d_out, int out_size, void* d_ws, size_t ws_size,
                              hipStream_t stream) {
    const float* x          = (const float*)d_in[0];
    const int*   edge_index = (const int*)d_in[1];
    const float* Wa         = (const float*)d_in[2];
    const float* ba         = (const float*)d_in[3];
    const float* Wb         = (const float*)d_in[4];
    const float* bb         = (const float*)d_in[5];
    float* out = (float*)d_out;

    const size_t x_bytes   = (size_t)N_NODES * N_FEAT * 2;          // 12,800,000
    const size_t su_bytes  = (size_t)N_POWERS * NB * CAPB * 4;      //  7,864,320
    const size_t inv_bytes = (size_t)N_POWERS * N_EDGES * 4;        //  7,200,000
    const size_t wa_bytes  = 2304;
    const size_t cur_bytes = N_POWERS * NB * 4;                     //      1,536
    const size_t need_full = x_bytes + su_bytes + inv_bytes + wa_bytes + cur_bytes;

    if (ws_size >= need_full) {
        char* w = (char*)d_ws;
        unsigned* xh  = (unsigned*)w;
        unsigned* su  = (unsigned*)(w + x_bytes);
        int*      inv = (int*)(w + x_bytes + su_bytes);
        unsigned* wah = (unsigned*)(w + x_bytes + su_bytes + inv_bytes);
        int*      cur = (int*)(w + x_bytes + su_bytes + inv_bytes + wa_bytes);

        conv_x_plain<<<N_NODES * N_FEAT / 2048, 256, 0, stream>>>(x, xh, Wa, wah, cur);
        scatter_onepass<<<dim3(NCHUNK, N_POWERS), 256, 0, stream>>>(edge_index, su, inv, cur);
        dim3 grid(NB * (CAPB / EDGES_PER_BLK), N_POWERS);   // (2048, 3)
        adj_kernel_sorted<<<grid, 256, 0, stream>>>(xh, su, cur, wah, ba, Wb, bb);
        unscatter_kernel<<<dim3((N_EDGES / 4 + 255) / 256, N_POWERS), 256, 0, stream>>>(
            su, inv, out);
    } else if (ws_size >= x_bytes + wa_bytes) {
        unsigned* xh  = (unsigned*)d_ws;
        unsigned* wah = (unsigned*)((char*)d_ws + x_bytes);
        conv_x_plain<<<N_NODES * N_FEAT / 2048, 256, 0, stream>>>(x, xh, Wa, wah, nullptr);
        dim3 grid(N_EDGES / EDGES_PER_BLK, N_POWERS);
        adj_kernel_f16<<<grid, 256, 0, stream>>>(xh, wah, edge_index, ba, Wb, bb, out);
    } else {
        dim3 grid((N_EDGES + 15) / 16, N_POWERS);
        adj_kernel_f32<<<grid, 256, 0, stream>>>(x, edge_index, Wa, ba, Wb, bb, out);
    }
}